// Round 2
// baseline (2293.768 us; speedup 1.0000x reference)
//
#include <hip/hip_runtime.h>
#include <hip/hip_bf16.h>
#include <math.h>

#define NN 20000
#define EE 320000
#define PCOLS 2016   // [q 384 | k 384 | v 384 | qp 288 | kp 288 | vp 288]
#define FCOLS 1440   // [p2n 384 | node 384 | loc 288 | nrm 96 | dirn 288]

__device__ __forceinline__ unsigned enc_f(float f) {
  unsigned u = __float_as_uint(f);
  return (u & 0x80000000u) ? ~u : (u | 0x80000000u);
}
__device__ __forceinline__ float dec_f(unsigned u) {
  return (u & 0x80000000u) ? __uint_as_float(u ^ 0x80000000u) : __uint_as_float(~u);
}

template<typename PT> __device__ __forceinline__ float ldp(const PT* p);
template<> __device__ __forceinline__ float ldp<float>(const float* p) { return *p; }
template<> __device__ __forceinline__ float ldp<__hip_bfloat16>(const __hip_bfloat16* p) { return __bfloat162float(*p); }
template<typename PT> __device__ __forceinline__ void stp(PT* p, float v);
template<> __device__ __forceinline__ void stp<float>(float* p, float v) { *p = v; }
template<> __device__ __forceinline__ void stp<__hip_bfloat16>(__hip_bfloat16* p, float v) { *p = __float2bfloat16(v); }

// ---------------- projections: P[n, 0..2015] = x[n] @ [Wq|Wk|Wv|Wqp|Wkp|Wvp]
template<typename PT>
__global__ __launch_bounds__(256) void proj_gemm(
    const float* __restrict__ x,
    const float* __restrict__ Wq, const float* __restrict__ Wk, const float* __restrict__ Wv,
    const float* __restrict__ Wqp, const float* __restrict__ Wkp, const float* __restrict__ Wvp,
    PT* __restrict__ P)
{
  __shared__ float As[16][33];
  __shared__ float Bs[32][128];
  int t = threadIdx.x;
  int n0 = blockIdx.x * 16;
  int c0 = blockIdx.y * 128;
  int col = t & 127, rpair = t >> 7;
  float acc[8] = {0,0,0,0,0,0,0,0};
  for (int k0 = 0; k0 < 128; k0 += 32) {
    #pragma unroll
    for (int q = 0; q < 2; q++) {
      int idx = t + 256*q; int r = idx >> 5, kk = idx & 31;
      As[r][kk] = x[(size_t)(n0+r)*128 + k0 + kk];
    }
    #pragma unroll
    for (int q = 0; q < 16; q++) {
      int idx = t + 256*q; int kk = idx >> 7, cl = idx & 127;
      int c = c0 + cl;
      float w = 0.f;
      if (c < 384)       w = Wq[(k0+kk)*384 + c];
      else if (c < 768)  w = Wk[(k0+kk)*384 + (c-384)];
      else if (c < 1152) w = Wv[(k0+kk)*384 + (c-768)];
      else if (c < 1440) w = Wqp[(k0+kk)*288 + (c-1152)];
      else if (c < 1728) w = Wkp[(k0+kk)*288 + (c-1440)];
      else if (c < 2016) w = Wvp[(k0+kk)*288 + (c-1728)];
      Bs[kk][cl] = w;
    }
    __syncthreads();
    for (int kk = 0; kk < 32; kk++) {
      float b = Bs[kk][col];
      #pragma unroll
      for (int j = 0; j < 8; j++) acc[j] += As[rpair*8+j][kk] * b;
    }
    __syncthreads();
  }
  int c = c0 + col;
  if (c < PCOLS) {
    #pragma unroll
    for (int j = 0; j < 8; j++) stp(&P[(size_t)(n0 + rpair*8 + j)*PCOLS + c], acc[j]);
  }
}

// ---------------- point transform (in place): p_global = R p_local + t  (qp,kp,vp)
template<typename PT>
__global__ void transform_pts(const float* __restrict__ R, const float* __restrict__ tr,
                              PT* __restrict__ P)
{
  int idx = blockIdx.x*256 + threadIdx.x;   // N*288 point tasks (288 pts/node)
  if (idx >= NN*288) return;
  int n = idx / 288, rem = idx - n*288;
  PT* p = P + (size_t)n*PCOLS + 1152 + rem*3;
  float l0 = ldp(p), l1 = ldp(p+1), l2 = ldp(p+2);
  const float* Rn = R + n*9;
  float t0 = tr[n*3], t1 = tr[n*3+1], t2 = tr[n*3+2];
  stp(p,   Rn[0]*l0 + Rn[1]*l1 + Rn[2]*l2 + t0);
  stp(p+1, Rn[3]*l0 + Rn[4]*l1 + Rn[5]*l2 + t1);
  stp(p+2, Rn[6]*l0 + Rn[7]*l1 + Rn[8]*l2 + t2);
}

// ---------------- CSR build
__global__ void count_edges(const int* __restrict__ ei, int* __restrict__ cnt)
{
  int e = blockIdx.x*256 + threadIdx.x;
  if (e < EE) atomicAdd(&cnt[ei[e]], 1);
}

__global__ __launch_bounds__(1024) void scan_csr(const int* __restrict__ cnt,
                                                 int* __restrict__ rowptr,
                                                 int* __restrict__ cursor)
{
  __shared__ int part[1024];
  int t = threadIdx.x;
  int base = t*20;
  int loc[20];
  int s = 0;
  #pragma unroll
  for (int i = 0; i < 20; i++) {
    int idx = base + i;
    int c = (idx < NN) ? cnt[idx] : 0;
    loc[i] = s; s += c;
  }
  part[t] = s;
  __syncthreads();
  for (int off = 1; off < 1024; off <<= 1) {
    int v = (t >= off) ? part[t-off] : 0;
    __syncthreads();
    part[t] += v;
    __syncthreads();
  }
  int pre = (t == 0) ? 0 : part[t-1];
  #pragma unroll
  for (int i = 0; i < 20; i++) {
    int idx = base + i;
    if (idx < NN) { rowptr[idx] = pre + loc[i]; cursor[idx] = pre + loc[i]; }
  }
  if (t == 1023) rowptr[NN] = part[1023];
}

__global__ void fill_csr(const int* __restrict__ ei, int* __restrict__ cursor,
                         int* __restrict__ eidx)
{
  int e = blockIdx.x*256 + threadIdx.x;
  if (e >= EE) return;
  int pos = atomicAdd(&cursor[ei[e]], 1);
  eidx[pos] = e;
}

// ---------------- per-edge logits + segment max (one wave per edge)
template<typename PT>
__global__ __launch_bounds__(256) void edge_logits(
    const PT* __restrict__ P, const float* __restrict__ z, const int* __restrict__ ei,
    const float* __restrict__ Wpair, const float* __restrict__ spc,
    float* __restrict__ logits, unsigned* __restrict__ mbuf)
{
  __shared__ float cf[12];
  if (threadIdx.x < 12) cf[threadIdx.x] = log1pf(expf(spc[threadIdx.x])) * (1.f/12.f);
  __syncthreads();
  int e = blockIdx.x*4 + (threadIdx.x >> 6);
  int lane = threadIdx.x & 63;
  int half = lane >> 5, i = lane & 31;
  int src = ei[e], dst = ei[EE + e];
  const PT* qrow  = P + (size_t)src*PCOLS;
  const PT* krow  = P + (size_t)dst*PCOLS + 384;
  const PT* qprow = P + (size_t)src*PCOLS + 1152;
  const PT* kprow = P + (size_t)dst*PCOLS + 1440;
  float zv = z[(size_t)e*32 + i];
  const float inv_sqrt_qk = 0.17677669529663687f;  // 1/sqrt(32)
  const float inv_sqrt3   = 0.5773502691896258f;   // sqrt(1/3)
  for (int hh = 0; hh < 6; hh++) {
    int h = hh*2 + half;
    float part = ldp(&qrow[h*32 + i]) * ldp(&krow[h*32 + i]) * inv_sqrt_qk;
    part += zv * Wpair[i*12 + h];
    if (i < 24) {
      float d = ldp(&qprow[h*24 + i]) - ldp(&kprow[h*24 + i]);
      part -= cf[h] * d * d;
    }
    #pragma unroll
    for (int m = 16; m >= 1; m >>= 1) part += __shfl_xor(part, m);
    if (i == 0) {
      float lg = part * inv_sqrt3;
      logits[(size_t)e*12 + h] = lg;
      atomicMax(&mbuf[src*12 + h], enc_f(lg));
    }
  }
}

// ---------------- exp(logit - max) and segment sum
__global__ void exp_sum(const int* __restrict__ ei, const unsigned* __restrict__ mbuf,
                        float* __restrict__ logits, float* __restrict__ sbuf)
{
  int idx = blockIdx.x*256 + threadIdx.x;
  if (idx >= EE*12) return;
  int e = idx / 12, h = idx - e*12;
  int src = ei[e];
  float m = dec_f(mbuf[src*12 + h]);
  float ev = expf(logits[idx] - m);
  logits[idx] = ev;
  atomicAdd(&sbuf[src*12 + h], ev);
}

// ---------------- fused CSR gather + spatial + Wo GEMV (8 nodes/block)
template<typename PT>
__global__ __launch_bounds__(256) void gather_wo(
    const PT* __restrict__ P, const float* __restrict__ z, const int* __restrict__ ei,
    const float* __restrict__ alphaE, const float* __restrict__ SB,
    const int* __restrict__ rowptr, const int* __restrict__ eidx,
    const float* __restrict__ R, const float* __restrict__ tr,
    const float* __restrict__ Wo, const float* __restrict__ bo,
    const float* __restrict__ x, float* __restrict__ xo)
{
  __shared__ float feat[8][FCOLS];
  __shared__ float agg[8][288];
  int t = threadIdx.x;
  int n0 = blockIdx.x * 8;

  // slot metadata (5 slots per thread covering 1056 accumulation lanes)
  int  sA[5]; int hA[5];
  #pragma unroll
  for (int j = 0; j < 5; j++) {
    int s = t + 256*j; sA[j] = s;
    int h = 0;
    if (s < 384) h = s >> 5;
    else if (s < 768) h = (s-384) >> 5;
    else if (s < 1056) h = (s-768) / 24;
    hA[j] = h;
  }

  for (int r = 0; r < 8; r++) {
    int n = n0 + r;
    float invS[5];
    #pragma unroll
    for (int j = 0; j < 5; j++)
      invS[j] = (sA[j] < 1056) ? (1.f / SB[n*12 + hA[j]]) : 0.f;
    float acc[5] = {0,0,0,0,0};
    int beg = rowptr[n], end = rowptr[n+1];
    for (int q = beg; q < end; q++) {
      int e = eidx[q];
      int dst = ei[EE + e];
      const float* aE = alphaE + (size_t)e*12;
      const PT* Pd = P + (size_t)dst*PCOLS;
      #pragma unroll
      for (int j = 0; j < 5; j++) {
        int s = sA[j];
        if (s >= 1056) continue;
        float a = aE[hA[j]] * invS[j];
        float v;
        if (s < 384)      v = z[(size_t)e*32 + (s & 31)];
        else if (s < 768) v = ldp(&Pd[384 + s]);    // 768 + (s-384)
        else              v = ldp(&Pd[960 + s]);    // 1728 + (s-768)
        acc[j] += a * v;
      }
    }
    #pragma unroll
    for (int j = 0; j < 5; j++) {
      int s = sA[j];
      if (s < 768) feat[r][s] = acc[j];
      else if (s < 1056) agg[r][s-768] = acc[j];
    }
  }
  __syncthreads();

  // spatial: loc = R^T(agg - t), nrm, dirn   (8 nodes x 96 points = 768 tasks)
  #pragma unroll
  for (int k = 0; k < 3; k++) {
    int idx = t + 256*k;
    int r = idx / 96, pt = idx - r*96;
    int n = n0 + r;
    const float* Rn = R + n*9;
    float d0 = agg[r][pt*3+0] - tr[n*3+0];
    float d1 = agg[r][pt*3+1] - tr[n*3+1];
    float d2 = agg[r][pt*3+2] - tr[n*3+2];
    float l0 = Rn[0]*d0 + Rn[3]*d1 + Rn[6]*d2;
    float l1 = Rn[1]*d0 + Rn[4]*d1 + Rn[7]*d2;
    float l2 = Rn[2]*d0 + Rn[5]*d1 + Rn[8]*d2;
    float nr = sqrtf(l0*l0 + l1*l1 + l2*l2);
    float inv = 1.f / fmaxf(nr, 1e-8f);
    feat[r][768 + pt*3+0] = l0; feat[r][768 + pt*3+1] = l1; feat[r][768 + pt*3+2] = l2;
    feat[r][1056 + pt] = nr;
    feat[r][1152 + pt*3+0] = l0*inv; feat[r][1152 + pt*3+1] = l1*inv; feat[r][1152 + pt*3+2] = l2*inv;
  }
  __syncthreads();

  // GEMV: xo[n] = feat[n] @ Wo + bo + x[n]
  int col = t & 127, rset = t >> 7;
  float o[4] = {0,0,0,0};
  #pragma unroll 4
  for (int i = 0; i < FCOLS; i++) {
    float w = Wo[i*128 + col];
    #pragma unroll
    for (int j = 0; j < 4; j++) o[j] += feat[rset*4 + j][i] * w;
  }
  #pragma unroll
  for (int j = 0; j < 4; j++) {
    int n = n0 + rset*4 + j;
    xo[(size_t)n*128 + col] = o[j] + bo[col] + x[(size_t)n*128 + col];
  }
}

// ---------------- LN1 -> MLP -> residual -> LN2, 8 nodes per block (in-place on xo)
__global__ __launch_bounds__(256) void lnmlp(
    const float* __restrict__ xo,
    const float* __restrict__ g1, const float* __restrict__ b1v,
    const float* __restrict__ w1, const float* __restrict__ bb1,
    const float* __restrict__ w2, const float* __restrict__ bb2,
    const float* __restrict__ w3, const float* __restrict__ bb3,
    const float* __restrict__ g2, const float* __restrict__ b2v,
    float* __restrict__ out)
{
  __shared__ float hs[8][128];
  __shared__ float ms[8][128];
  __shared__ float ys[8][128];
  __shared__ float mu_s[8], rs_s[8];
  int t = threadIdx.x;
  int n0 = blockIdx.x * 8;
  int c = t & 127, rset = t >> 7;
  int w = t >> 6, lane = t & 63;

  for (int r = rset; r < 8; r += 2) ys[r][c] = xo[(size_t)(n0+r)*128 + c];
  __syncthreads();
  for (int q = 0; q < 2; q++) {
    int r = w*2 + q;
    float v0 = ys[r][lane], v1 = ys[r][lane+64];
    float s = v0 + v1, ss = v0*v0 + v1*v1;
    #pragma unroll
    for (int m = 32; m >= 1; m >>= 1) { s += __shfl_xor(s, m); ss += __shfl_xor(ss, m); }
    if (lane == 0) { float mu = s*(1.f/128.f); mu_s[r] = mu; rs_s[r] = rsqrtf(ss*(1.f/128.f) - mu*mu + 1e-5f); }
  }
  __syncthreads();
  for (int r = rset; r < 8; r += 2) hs[r][c] = (ys[r][c] - mu_s[r]) * rs_s[r] * g1[c] + b1v[c];
  __syncthreads();
  {
    float acc[4] = {0,0,0,0};
    for (int i = 0; i < 128; i++) {
      float wv = w1[i*128 + c];
      #pragma unroll
      for (int j = 0; j < 4; j++) acc[j] += hs[rset*4+j][i] * wv;
    }
    #pragma unroll
    for (int j = 0; j < 4; j++) ms[rset*4+j][c] = fmaxf(acc[j] + bb1[c], 0.f);
  }
  __syncthreads();
  {
    float acc[4] = {0,0,0,0};
    for (int i = 0; i < 128; i++) {
      float wv = w2[i*128 + c];
      #pragma unroll
      for (int j = 0; j < 4; j++) acc[j] += ms[rset*4+j][i] * wv;
    }
    #pragma unroll
    for (int j = 0; j < 4; j++) ys[rset*4+j][c] = fmaxf(acc[j] + bb2[c], 0.f);
  }
  __syncthreads();
  {
    float acc[4] = {0,0,0,0};
    for (int i = 0; i < 128; i++) {
      float wv = w3[i*128 + c];
      #pragma unroll
      for (int j = 0; j < 4; j++) acc[j] += ys[rset*4+j][i] * wv;
    }
    #pragma unroll
    for (int j = 0; j < 4; j++) ms[rset*4+j][c] = hs[rset*4+j][c] + acc[j] + bb3[c];
  }
  __syncthreads();
  for (int q = 0; q < 2; q++) {
    int r = w*2 + q;
    float v0 = ms[r][lane], v1 = ms[r][lane+64];
    float s = v0 + v1, ss = v0*v0 + v1*v1;
    #pragma unroll
    for (int m = 32; m >= 1; m >>= 1) { s += __shfl_xor(s, m); ss += __shfl_xor(ss, m); }
    if (lane == 0) { float mu = s*(1.f/128.f); mu_s[r] = mu; rs_s[r] = rsqrtf(ss*(1.f/128.f) - mu*mu + 1e-5f); }
  }
  __syncthreads();
  for (int r = rset; r < 8; r += 2)
    out[(size_t)(n0+r)*128 + c] = (ms[r][c] - mu_s[r]) * rs_s[r] * g2[c] + b2v[c];
}

__global__ void diag_ws(float* out, float v)
{
  if (blockIdx.x == 0 && threadIdx.x == 0) out[0] = v;
}

// ---------------- host side ----------------
struct Args {
  const float *R, *tr, *x, *z, *Wq, *Wk, *Wv, *Wpair, *spc, *Wqp, *Wkp, *Wvp;
  const float *Wo, *bo, *g1, *b1v, *w1, *bb1, *w2, *bb2, *w3, *bb3, *g2, *b2v;
  const int* ei;
  float* out;
};

template<typename PT>
static void run_all(const Args& a, char* ws, hipStream_t stream)
{
  auto al = [](size_t v) { return (v + 255) & ~(size_t)255; };
  size_t off = 0;
  PT* P = (PT*)(ws + off);          off += al((size_t)NN*PCOLS*sizeof(PT));
  float* LOG = (float*)(ws + off);  off += al((size_t)EE*12*sizeof(float));
  unsigned* MB = (unsigned*)(ws + off); off += al((size_t)NN*12*sizeof(unsigned));
  float* SB = (float*)(ws + off);   off += al((size_t)NN*12*sizeof(float));
  int* cnt = (int*)(ws + off);      off += al((size_t)NN*sizeof(int));
  int* rowptr = (int*)(ws + off);   off += al((size_t)(NN+1)*sizeof(int));
  int* cursor = (int*)(ws + off);   off += al((size_t)NN*sizeof(int));
  int* eidx = (int*)(ws + off);     off += al((size_t)EE*sizeof(int));
  float* xo = a.out;                // alias output buffer as XO temp

  hipMemsetAsync(MB, 0, (size_t)NN*12*sizeof(unsigned), stream);
  hipMemsetAsync(SB, 0, (size_t)NN*12*sizeof(float), stream);
  hipMemsetAsync(cnt, 0, (size_t)NN*sizeof(int), stream);

  proj_gemm<PT><<<dim3(NN/16, 16), 256, 0, stream>>>(a.x, a.Wq, a.Wk, a.Wv, a.Wqp, a.Wkp, a.Wvp, P);
  transform_pts<PT><<<(NN*288)/256, 256, 0, stream>>>(a.R, a.tr, P);
  count_edges<<<EE/256, 256, 0, stream>>>(a.ei, cnt);
  scan_csr<<<1, 1024, 0, stream>>>(cnt, rowptr, cursor);
  fill_csr<<<EE/256, 256, 0, stream>>>(a.ei, cursor, eidx);
  edge_logits<PT><<<EE/4, 256, 0, stream>>>(P, a.z, a.ei, a.Wpair, a.spc, LOG, MB);
  exp_sum<<<(EE*12)/256, 256, 0, stream>>>(a.ei, MB, LOG, SB);
  gather_wo<PT><<<NN/8, 256, 0, stream>>>(P, a.z, a.ei, LOG, SB, rowptr, eidx,
                                          a.R, a.tr, a.Wo, a.bo, a.x, xo);
  lnmlp<<<NN/8, 256, 0, stream>>>(xo, a.g1, a.b1v, a.w1, a.bb1, a.w2, a.bb2,
                                  a.w3, a.bb3, a.g2, a.b2v, a.out);
}

extern "C" void kernel_launch(void* const* d_in, const int* in_sizes, int n_in,
                              void* d_out, int out_size, void* d_ws, size_t ws_size,
                              hipStream_t stream)
{
  Args a;
  a.R     = (const float*)d_in[0];
  a.tr    = (const float*)d_in[1];
  a.x     = (const float*)d_in[2];
  a.z     = (const float*)d_in[3];
  a.ei    = (const int*)  d_in[4];
  a.Wq    = (const float*)d_in[5];
  a.Wk    = (const float*)d_in[6];
  a.Wv    = (const float*)d_in[7];
  a.Wpair = (const float*)d_in[8];
  a.spc   = (const float*)d_in[9];
  a.Wqp   = (const float*)d_in[10];
  a.Wkp   = (const float*)d_in[11];
  a.Wvp   = (const float*)d_in[12];
  a.Wo    = (const float*)d_in[13];
  a.bo    = (const float*)d_in[14];
  a.g1    = (const float*)d_in[15];
  a.b1v   = (const float*)d_in[16];
  a.w1    = (const float*)d_in[17];
  a.bb1   = (const float*)d_in[18];
  a.w2    = (const float*)d_in[19];
  a.bb2   = (const float*)d_in[20];
  a.w3    = (const float*)d_in[21];
  a.bb3   = (const float*)d_in[22];
  a.g2    = (const float*)d_in[23];
  a.b2v   = (const float*)d_in[24];
  a.out   = (float*)d_out;

  auto al = [](size_t v) { return (v + 255) & ~(size_t)255; };
  size_t common = al((size_t)EE*12*4) + al((size_t)NN*12*4)*2 + al((size_t)NN*4)*2 +
                  al((size_t)(NN+1)*4) + al((size_t)EE*4);
  size_t need_f32  = al((size_t)NN*PCOLS*4) + common;
  size_t need_bf16 = al((size_t)NN*PCOLS*2) + common;

  if (ws_size >= need_f32) {
    run_all<float>(a, (char*)d_ws, stream);
  } else if (ws_size >= need_bf16) {
    run_all<__hip_bfloat16>(a, (char*)d_ws, stream);
  } else {
    // nothing fits: encode ws_size (in MB) into out[0] as a diagnostic
    diag_ws<<<1, 64, 0, stream>>>((float*)d_out, (float)((double)ws_size / (1024.0*1024.0)));
  }
}

// Round 3
// 1007.629 us; speedup vs baseline: 2.2764x; 2.2764x over previous
//
#include <hip/hip_runtime.h>
#include <hip/hip_bf16.h>
#include <math.h>

#define NN 20000
#define EE 320000
#define QKV_COLS 1152   // [q 0..383 | k 384..767 | v 768..1151]
#define PTS_COLS 864    // [qp 0..287 | kp 288..575 | vp 576..863]
#define FCOLS 1440      // [p2n 384 | node 384 | loc 288 | nrm 96 | dirn 288]

__device__ __forceinline__ unsigned enc_f(float f) {
  unsigned u = __float_as_uint(f);
  return (u & 0x80000000u) ? ~u : (u | 0x80000000u);
}
__device__ __forceinline__ float dec_f(unsigned u) {
  return (u & 0x80000000u) ? __uint_as_float(u ^ 0x80000000u) : __uint_as_float(~u);
}
__device__ __forceinline__ float b2f(unsigned short u) {
  return __uint_as_float(((unsigned)u) << 16);
}

template<typename PT> __device__ __forceinline__ float ldp(const PT* p);
template<> __device__ __forceinline__ float ldp<float>(const float* p) { return *p; }
template<> __device__ __forceinline__ float ldp<__hip_bfloat16>(const __hip_bfloat16* p) { return __bfloat162float(*p); }
template<typename PT> __device__ __forceinline__ void stp(PT* p, float v);
template<> __device__ __forceinline__ void stp<float>(float* p, float v) { *p = v; }
template<> __device__ __forceinline__ void stp<__hip_bfloat16>(__hip_bfloat16* p, float v) { *p = __float2bfloat16(v); }

// ---------------- projections: [Pqkv | Ppts](n) = x[n] @ [Wq|Wk|Wv | Wqp|Wkp|Wvp]
// 32x128 tile, 4x4 register block per thread.
template<typename TA, typename TP>
__global__ __launch_bounds__(256) void proj_gemm(
    const float* __restrict__ x,
    const float* __restrict__ Wq, const float* __restrict__ Wk, const float* __restrict__ Wv,
    const float* __restrict__ Wqp, const float* __restrict__ Wkp, const float* __restrict__ Wvp,
    TA* __restrict__ Pqkv, TP* __restrict__ Ppts)
{
  __shared__ float Ast[32][36];
  __shared__ float Bs[32][132];
  const int t = threadIdx.x;
  const int n0 = blockIdx.x * 32;
  const int c0 = blockIdx.y * 128;
  const int tx = t & 31, ty = t >> 5;
  // fixed B-column per thread
  const int cl = t & 127, kset = t >> 7;
  const int c = c0 + cl;
  const float* wcol = nullptr; int wstr = 0;
  if      (c < 384)  { wcol = Wq  + c;        wstr = 384; }
  else if (c < 768)  { wcol = Wk  + (c-384);  wstr = 384; }
  else if (c < 1152) { wcol = Wv  + (c-768);  wstr = 384; }
  else if (c < 1440) { wcol = Wqp + (c-1152); wstr = 288; }
  else if (c < 1728) { wcol = Wkp + (c-1440); wstr = 288; }
  else if (c < 2016) { wcol = Wvp + (c-1728); wstr = 288; }
  float acc[4][4] = {};
  const int ar = t >> 3, akc = (t & 7) * 4;
  for (int k0 = 0; k0 < 128; k0 += 32) {
    float4 av4 = *(const float4*)&x[(size_t)(n0 + ar)*128 + k0 + akc];
    Ast[akc+0][ar] = av4.x; Ast[akc+1][ar] = av4.y;
    Ast[akc+2][ar] = av4.z; Ast[akc+3][ar] = av4.w;
    #pragma unroll
    for (int u = 0; u < 16; u++) {
      int kk = kset + 2*u;
      Bs[kk][cl] = wcol ? wcol[(size_t)(k0 + kk)*wstr] : 0.f;
    }
    __syncthreads();
    #pragma unroll
    for (int kk = 0; kk < 32; kk++) {
      float4 a4 = *(const float4*)&Ast[kk][ty*4];
      float4 b4 = *(const float4*)&Bs[kk][tx*4];
      float av[4] = {a4.x, a4.y, a4.z, a4.w};
      float bv[4] = {b4.x, b4.y, b4.z, b4.w};
      #pragma unroll
      for (int i2 = 0; i2 < 4; i2++)
        #pragma unroll
        for (int j2 = 0; j2 < 4; j2++)
          acc[i2][j2] += av[i2] * bv[j2];
    }
    __syncthreads();
  }
  const int gc = c0 + tx*4;
  #pragma unroll
  for (int i2 = 0; i2 < 4; i2++) {
    int r = n0 + ty*4 + i2;
    if (gc < 1152) {
      TA* dstp = Pqkv + (size_t)r*QKV_COLS + gc;
      #pragma unroll
      for (int j2 = 0; j2 < 4; j2++) stp(&dstp[j2], acc[i2][j2]);
    } else {
      TP* dstp = Ppts + (size_t)r*PTS_COLS + (gc - 1152);
      #pragma unroll
      for (int j2 = 0; j2 < 4; j2++) if (gc + j2 < 2016) stp(&dstp[j2], acc[i2][j2]);
    }
  }
}

// ---------------- point transform (in place on Ppts): p_global = R p_local + t
template<typename TP>
__global__ void transform_pts(const float* __restrict__ R, const float* __restrict__ tr,
                              TP* __restrict__ Ppts)
{
  int idx = blockIdx.x*256 + threadIdx.x;   // N * 288 point-triples
  if (idx >= NN*288) return;
  int n = idx / 288, rem = idx - n*288;
  TP* p = Ppts + (size_t)n*PTS_COLS + rem*3;
  float l0 = ldp(p), l1 = ldp(p+1), l2 = ldp(p+2);
  const float* Rn = R + (size_t)n*9;
  float t0 = tr[n*3], t1 = tr[n*3+1], t2 = tr[n*3+2];
  stp(p,   Rn[0]*l0 + Rn[1]*l1 + Rn[2]*l2 + t0);
  stp(p+1, Rn[3]*l0 + Rn[4]*l1 + Rn[5]*l2 + t1);
  stp(p+2, Rn[6]*l0 + Rn[7]*l1 + Rn[8]*l2 + t2);
}

// ---------------- CSR build
__global__ void count_edges(const int* __restrict__ ei, int* __restrict__ cnt)
{
  int e = blockIdx.x*256 + threadIdx.x;
  if (e < EE) atomicAdd(&cnt[ei[e]], 1);
}

__global__ __launch_bounds__(1024) void scan_csr(const int* __restrict__ cnt,
                                                 int* __restrict__ rowptr,
                                                 int* __restrict__ cursor)
{
  __shared__ int part[1024];
  int t = threadIdx.x;
  int base = t*20;
  int loc[20];
  int s = 0;
  #pragma unroll
  for (int i = 0; i < 20; i++) {
    int idx = base + i;
    int cc = (idx < NN) ? cnt[idx] : 0;
    loc[i] = s; s += cc;
  }
  part[t] = s;
  __syncthreads();
  for (int off = 1; off < 1024; off <<= 1) {
    int v = (t >= off) ? part[t-off] : 0;
    __syncthreads();
    part[t] += v;
    __syncthreads();
  }
  int pre = (t == 0) ? 0 : part[t-1];
  #pragma unroll
  for (int i = 0; i < 20; i++) {
    int idx = base + i;
    if (idx < NN) { rowptr[idx] = pre + loc[i]; cursor[idx] = pre + loc[i]; }
  }
  if (t == 1023) rowptr[NN] = part[1023];
}

__global__ void fill_csr(const int* __restrict__ ei, int* __restrict__ cursor,
                         int* __restrict__ eidx)
{
  int e = blockIdx.x*256 + threadIdx.x;
  if (e >= EE) return;
  int pos = atomicAdd(&cursor[ei[e]], 1);
  eidx[pos] = e;
}

// ---------------- per-node fused logits + softmax -> normalized ALPHA[q*12+h]
template<typename TA, typename TP>
__global__ __launch_bounds__(256) void node_logits(
    const TA* __restrict__ Pqkv, const TP* __restrict__ Ppts,
    const float* __restrict__ z, const int* __restrict__ ei,
    const float* __restrict__ Wpair, const float* __restrict__ spc,
    const int* __restrict__ rowptr, const int* __restrict__ eidx,
    float* __restrict__ ALPHA)
{
  __shared__ float qrow[384], qprow[288], wp[384], cf[12], ssum[12];
  __shared__ unsigned ms[12];
  const int n = blockIdx.x, t = threadIdx.x;
  const int beg = rowptr[n], end = rowptr[n+1], deg = end - beg;
  if (t < 12) { cf[t] = log1pf(expf(spc[t])) * (1.f/12.f); ms[t] = 0u; ssum[t] = 0.f; }
  for (int i = t; i < 384; i += 256) { qrow[i] = ldp(&Pqkv[(size_t)n*QKV_COLS + i]); wp[i] = Wpair[i]; }
  for (int i = t; i < 288; i += 256) qprow[i] = ldp(&Ppts[(size_t)n*PTS_COLS + i]);
  __syncthreads();
  if (deg == 0) return;
  const int wid = t >> 6, lane = t & 63, half = lane >> 5, li = lane & 31;
  const float inv_sqrt_qk = 0.17677669529663687f;  // 1/sqrt(32)
  const float inv_sqrt3   = 0.5773502691896258f;   // sqrt(1/3)
  // pass A: raw logits per edge (one wave per edge, 2 heads per half-wave)
  for (int q = beg + wid; q < end; q += 4) {
    int e = eidx[q];
    int dst = ei[EE + e];
    const TA* kr  = Pqkv + (size_t)dst*QKV_COLS + 384;
    const TP* kpr = Ppts + (size_t)dst*PTS_COLS + 288;
    float zv = z[(size_t)e*32 + li];
    #pragma unroll
    for (int hh = 0; hh < 6; hh++) {
      int h = hh*2 + half;
      float part = qrow[h*32 + li] * ldp(&kr[h*32 + li]) * inv_sqrt_qk;
      part += zv * wp[li*12 + h];
      if (li < 24) { float d = qprow[h*24 + li] - ldp(&kpr[h*24 + li]); part -= cf[h]*d*d; }
      #pragma unroll
      for (int m2 = 16; m2 >= 1; m2 >>= 1) part += __shfl_xor(part, m2);
      if (li == 0) {
        float lg = part * inv_sqrt3;
        ALPHA[(size_t)q*12 + h] = lg;
        atomicMax(&ms[h], enc_f(lg));
      }
    }
  }
  __syncthreads();
  float* An = ALPHA + (size_t)beg*12;
  const int tot = deg*12;
  // pass B: exp(l - m), accumulate sums in LDS
  for (int idx = t; idx < tot; idx += 256) {
    int h = idx % 12;
    float ev = expf(An[idx] - dec_f(ms[h]));
    An[idx] = ev;
    atomicAdd(&ssum[h], ev);
  }
  __syncthreads();
  // pass C: normalize
  for (int idx = t; idx < tot; idx += 256) {
    int h = idx % 12;
    An[idx] *= (1.f / ssum[h]);
  }
}

// ---------------- per-node CSR aggregation -> bf16 feat panel (with spatial transform)
template<typename TA, typename TP>
__global__ __launch_bounds__(256) void aggregate(
    const TA* __restrict__ Pqkv, const TP* __restrict__ Ppts,
    const float* __restrict__ z, const int* __restrict__ ei,
    const float* __restrict__ ALPHA,
    const int* __restrict__ rowptr, const int* __restrict__ eidx,
    const float* __restrict__ R, const float* __restrict__ tr,
    __hip_bfloat16* __restrict__ featB)
{
  __shared__ int sE[64], sD[64];
  __shared__ float sZ[64][32];
  __shared__ float sA[64][12];
  __shared__ float sAgg[288];
  const int n = blockIdx.x, t = threadIdx.x;
  const int beg = rowptr[n], end = rowptr[n+1];
  // per-thread slot->head classes (slots s = t, 256+t, 512+t, 768+t, 1024+t)
  const int h0 = t >> 5;                                        // z, heads 0..7
  const int h1 = (t < 128) ? (8 + (t >> 5)) : ((t - 128) >> 5); // z heads 8..11 | V heads 0..3
  const int h2 = 4 + (t >> 5);                                  // V heads 4..11
  const int h3 = t / 24;                                        // VP
  const int h4 = (t < 32) ? ((t + 256) / 24) : 0;               // VP tail
  const int zc = t & 31;
  float a0=0.f, a1=0.f, a2=0.f, a3=0.f, a4=0.f;
  for (int c0 = beg; c0 < end; c0 += 64) {
    const int cn = min(64, end - c0);
    if (t < 64 && t < cn) { int e = eidx[c0 + t]; sE[t] = e; sD[t] = ei[EE + e]; }
    __syncthreads();
    #pragma unroll
    for (int u = 0; u < 8; u++) {
      int idx = t + 256*u; int j = idx >> 5;
      if (j < cn) sZ[j][idx & 31] = z[(size_t)sE[j]*32 + (idx & 31)];
    }
    #pragma unroll
    for (int u = 0; u < 3; u++) {
      int idx = t + 256*u;
      if (idx < cn*12) sA[idx/12][idx%12] = ALPHA[(size_t)c0*12 + idx];
    }
    __syncthreads();
    #pragma unroll 2
    for (int q = 0; q < cn; q++) {
      int dst = sD[q];
      const TA* Pq = Pqkv + (size_t)dst*QKV_COLS;
      const TP* Pp = Ppts + (size_t)dst*PTS_COLS;
      float zval = sZ[q][zc];
      a0 += sA[q][h0] * zval;
      if (t < 128) a1 += sA[q][h1] * zval;
      else         a1 += sA[q][h1] * ldp(&Pq[640 + t]);
      a2 += sA[q][h2] * ldp(&Pq[896 + t]);
      a3 += sA[q][h3] * ldp(&Pp[576 + t]);
      if (t < 32) a4 += sA[q][h4] * ldp(&Pp[832 + t]);
    }
    __syncthreads();
  }
  __hip_bfloat16* fr = featB + (size_t)n*FCOLS;
  fr[t]       = __float2bfloat16(a0);   // slots 0..255
  fr[256 + t] = __float2bfloat16(a1);   // slots 256..511 (p2n tail + V heads 0..3)
  fr[512 + t] = __float2bfloat16(a2);   // slots 512..767
  sAgg[t] = a3;
  if (t < 32) sAgg[256 + t] = a4;
  __syncthreads();
  if (t < 96) {
    int pt = t;
    const float* Rn = R + (size_t)n*9;
    float d0 = sAgg[pt*3+0] - tr[n*3+0];
    float d1 = sAgg[pt*3+1] - tr[n*3+1];
    float d2 = sAgg[pt*3+2] - tr[n*3+2];
    float l0 = Rn[0]*d0 + Rn[3]*d1 + Rn[6]*d2;
    float l1 = Rn[1]*d0 + Rn[4]*d1 + Rn[7]*d2;
    float l2 = Rn[2]*d0 + Rn[5]*d1 + Rn[8]*d2;
    float nr = sqrtf(l0*l0 + l1*l1 + l2*l2);
    float inv = 1.f / fmaxf(nr, 1e-8f);
    fr[768 + pt*3+0] = __float2bfloat16(l0);
    fr[768 + pt*3+1] = __float2bfloat16(l1);
    fr[768 + pt*3+2] = __float2bfloat16(l2);
    fr[1056 + pt]    = __float2bfloat16(nr);
    fr[1152 + pt*3+0] = __float2bfloat16(l0*inv);
    fr[1152 + pt*3+1] = __float2bfloat16(l1*inv);
    fr[1152 + pt*3+2] = __float2bfloat16(l2*inv);
  }
}

// ---------------- xo = x + featB @ Wo + bo   (32x128 tile, 4x4 register block)
__global__ __launch_bounds__(256) void wo_gemm(
    const __hip_bfloat16* __restrict__ featB, const float* __restrict__ Wo,
    const float* __restrict__ bo, const float* __restrict__ x, float* __restrict__ xo)
{
  __shared__ float Ast[32][36];
  __shared__ float Bs[32][132];
  const int t = threadIdx.x;
  const int n0 = blockIdx.x * 32;
  const int tx = t & 31, ty = t >> 5;
  const int cl = t & 127, kset = t >> 7;
  float acc[4][4] = {};
  const int ar = t >> 3, akc = (t & 7) * 4;
  for (int k0 = 0; k0 < FCOLS; k0 += 32) {
    {
      const __hip_bfloat16* ap = featB + (size_t)(n0 + ar)*FCOLS + k0 + akc;
      short4 raw = *(const short4*)(const void*)ap;
      Ast[akc+0][ar] = b2f((unsigned short)raw.x);
      Ast[akc+1][ar] = b2f((unsigned short)raw.y);
      Ast[akc+2][ar] = b2f((unsigned short)raw.z);
      Ast[akc+3][ar] = b2f((unsigned short)raw.w);
    }
    #pragma unroll
    for (int u = 0; u < 16; u++) {
      int kk = kset + 2*u;
      Bs[kk][cl] = Wo[(size_t)(k0 + kk)*128 + cl];
    }
    __syncthreads();
    #pragma unroll
    for (int kk = 0; kk < 32; kk++) {
      float4 a4 = *(const float4*)&Ast[kk][ty*4];
      float4 b4 = *(const float4*)&Bs[kk][tx*4];
      float av[4] = {a4.x, a4.y, a4.z, a4.w};
      float bv[4] = {b4.x, b4.y, b4.z, b4.w};
      #pragma unroll
      for (int i2 = 0; i2 < 4; i2++)
        #pragma unroll
        for (int j2 = 0; j2 < 4; j2++)
          acc[i2][j2] += av[i2] * bv[j2];
    }
    __syncthreads();
  }
  const int gc = tx*4;
  #pragma unroll
  for (int i2 = 0; i2 < 4; i2++) {
    int r = n0 + ty*4 + i2;
    float4 xr = *(const float4*)&x[(size_t)r*128 + gc];
    float xv[4] = {xr.x, xr.y, xr.z, xr.w};
    #pragma unroll
    for (int j2 = 0; j2 < 4; j2++)
      xo[(size_t)r*128 + gc + j2] = acc[i2][j2] + bo[gc + j2] + xv[j2];
  }
}

// ---------------- LN1 -> MLP -> residual -> LN2, 8 nodes per block (in-place on xo)
__global__ __launch_bounds__(256) void lnmlp(
    const float* __restrict__ xo,
    const float* __restrict__ g1, const float* __restrict__ b1v,
    const float* __restrict__ w1, const float* __restrict__ bb1,
    const float* __restrict__ w2, const float* __restrict__ bb2,
    const float* __restrict__ w3, const float* __restrict__ bb3,
    const float* __restrict__ g2, const float* __restrict__ b2v,
    float* __restrict__ out)
{
  __shared__ float hs[8][128];
  __shared__ float ms2[8][128];
  __shared__ float ys[8][128];
  __shared__ float mu_s[8], rs_s[8];
  int t = threadIdx.x;
  int n0 = blockIdx.x * 8;
  int c = t & 127, rset = t >> 7;
  int w = t >> 6, lane = t & 63;

  for (int r = rset; r < 8; r += 2) ys[r][c] = xo[(size_t)(n0+r)*128 + c];
  __syncthreads();
  for (int q = 0; q < 2; q++) {
    int r = w*2 + q;
    float v0 = ys[r][lane], v1 = ys[r][lane+64];
    float s = v0 + v1, ss = v0*v0 + v1*v1;
    #pragma unroll
    for (int m2 = 32; m2 >= 1; m2 >>= 1) { s += __shfl_xor(s, m2); ss += __shfl_xor(ss, m2); }
    if (lane == 0) { float mu = s*(1.f/128.f); mu_s[r] = mu; rs_s[r] = rsqrtf(ss*(1.f/128.f) - mu*mu + 1e-5f); }
  }
  __syncthreads();
  for (int r = rset; r < 8; r += 2) hs[r][c] = (ys[r][c] - mu_s[r]) * rs_s[r] * g1[c] + b1v[c];
  __syncthreads();
  {
    float acc[4] = {0,0,0,0};
    for (int i = 0; i < 128; i++) {
      float wv = w1[i*128 + c];
      #pragma unroll
      for (int j = 0; j < 4; j++) acc[j] += hs[rset*4+j][i] * wv;
    }
    #pragma unroll
    for (int j = 0; j < 4; j++) ms2[rset*4+j][c] = fmaxf(acc[j] + bb1[c], 0.f);
  }
  __syncthreads();
  {
    float acc[4] = {0,0,0,0};
    for (int i = 0; i < 128; i++) {
      float wv = w2[i*128 + c];
      #pragma unroll
      for (int j = 0; j < 4; j++) acc[j] += ms2[rset*4+j][i] * wv;
    }
    #pragma unroll
    for (int j = 0; j < 4; j++) ys[rset*4+j][c] = fmaxf(acc[j] + bb2[c], 0.f);
  }
  __syncthreads();
  {
    float acc[4] = {0,0,0,0};
    for (int i = 0; i < 128; i++) {
      float wv = w3[i*128 + c];
      #pragma unroll
      for (int j = 0; j < 4; j++) acc[j] += ys[rset*4+j][i] * wv;
    }
    #pragma unroll
    for (int j = 0; j < 4; j++) ms2[rset*4+j][c] = hs[rset*4+j][c] + acc[j] + bb3[c];
  }
  __syncthreads();
  for (int q = 0; q < 2; q++) {
    int r = w*2 + q;
    float v0 = ms2[r][lane], v1 = ms2[r][lane+64];
    float s = v0 + v1, ss = v0*v0 + v1*v1;
    #pragma unroll
    for (int m2 = 32; m2 >= 1; m2 >>= 1) { s += __shfl_xor(s, m2); ss += __shfl_xor(ss, m2); }
    if (lane == 0) { float mu = s*(1.f/128.f); mu_s[r] = mu; rs_s[r] = rsqrtf(ss*(1.f/128.f) - mu*mu + 1e-5f); }
  }
  __syncthreads();
  for (int r = rset; r < 8; r += 2)
    out[(size_t)(n0+r)*128 + c] = (ms2[r][c] - mu_s[r]) * rs_s[r] * g2[c] + b2v[c];
}

__global__ void diag_ws(float* out, float v)
{
  if (blockIdx.x == 0 && threadIdx.x == 0) out[0] = v;
}

// ---------------- host side ----------------
struct Args {
  const float *R, *tr, *x, *z, *Wq, *Wk, *Wv, *Wpair, *spc, *Wqp, *Wkp, *Wvp;
  const float *Wo, *bo, *g1, *b1v, *w1, *bb1, *w2, *bb2, *w3, *bb3, *g2, *b2v;
  const int* ei;
  float* out;
};

static inline size_t alup(size_t v) { return (v + 255) & ~(size_t)255; }

template<typename TA, typename TP>
static void run_all(const Args& a, char* ws, hipStream_t stream)
{
  size_t off = 0;
  TA* Pqkv = (TA*)(ws + off);       off += alup((size_t)NN*QKV_COLS*sizeof(TA));
  TP* Ppts = (TP*)(ws + off);       off += alup((size_t)NN*PTS_COLS*sizeof(TP));
  float* ALPHA = (float*)(ws + off); off += alup((size_t)EE*12*sizeof(float));
  int* cnt = (int*)(ws + off);      off += alup((size_t)NN*sizeof(int));
  int* rowptr = (int*)(ws + off);   off += alup((size_t)(NN+1)*sizeof(int));
  int* cursor = (int*)(ws + off);   off += alup((size_t)NN*sizeof(int));
  int* eidx = (int*)(ws + off);     off += alup((size_t)EE*sizeof(int));
  __hip_bfloat16* featB = (__hip_bfloat16*)(ws + off);
  float* xo = a.out;   // alias output buffer for the pre-LN activations

  hipMemsetAsync(cnt, 0, (size_t)NN*sizeof(int), stream);

  proj_gemm<TA,TP><<<dim3(NN/32, 16), 256, 0, stream>>>(a.x, a.Wq, a.Wk, a.Wv, a.Wqp, a.Wkp, a.Wvp, Pqkv, Ppts);
  transform_pts<TP><<<(NN*288)/256, 256, 0, stream>>>(a.R, a.tr, Ppts);
  count_edges<<<EE/256, 256, 0, stream>>>(a.ei, cnt);
  scan_csr<<<1, 1024, 0, stream>>>(cnt, rowptr, cursor);
  fill_csr<<<EE/256, 256, 0, stream>>>(a.ei, cursor, eidx);
  node_logits<TA,TP><<<NN, 256, 0, stream>>>(Pqkv, Ppts, a.z, a.ei, a.Wpair, a.spc, rowptr, eidx, ALPHA);
  aggregate<TA,TP><<<NN, 256, 0, stream>>>(Pqkv, Ppts, a.z, a.ei, ALPHA, rowptr, eidx, a.R, a.tr, featB);
  wo_gemm<<<NN/32, 256, 0, stream>>>(featB, a.Wo, a.bo, a.x, xo);
  lnmlp<<<NN/8, 256, 0, stream>>>(xo, a.g1, a.b1v, a.w1, a.bb1, a.w2, a.bb2,
                                  a.w3, a.bb3, a.g2, a.b2v, a.out);
}

extern "C" void kernel_launch(void* const* d_in, const int* in_sizes, int n_in,
                              void* d_out, int out_size, void* d_ws, size_t ws_size,
                              hipStream_t stream)
{
  Args a;
  a.R     = (const float*)d_in[0];
  a.tr    = (const float*)d_in[1];
  a.x     = (const float*)d_in[2];
  a.z     = (const float*)d_in[3];
  a.ei    = (const int*)  d_in[4];
  a.Wq    = (const float*)d_in[5];
  a.Wk    = (const float*)d_in[6];
  a.Wv    = (const float*)d_in[7];
  a.Wpair = (const float*)d_in[8];
  a.spc   = (const float*)d_in[9];
  a.Wqp   = (const float*)d_in[10];
  a.Wkp   = (const float*)d_in[11];
  a.Wvp   = (const float*)d_in[12];
  a.Wo    = (const float*)d_in[13];
  a.bo    = (const float*)d_in[14];
  a.g1    = (const float*)d_in[15];
  a.b1v   = (const float*)d_in[16];
  a.w1    = (const float*)d_in[17];
  a.bb1   = (const float*)d_in[18];
  a.w2    = (const float*)d_in[19];
  a.bb2   = (const float*)d_in[20];
  a.w3    = (const float*)d_in[21];
  a.bb3   = (const float*)d_in[22];
  a.g2    = (const float*)d_in[23];
  a.b2v   = (const float*)d_in[24];
  a.out   = (float*)d_out;

  size_t common = alup((size_t)EE*12*4) + alup((size_t)NN*4) + alup((size_t)(NN+1)*4) +
                  alup((size_t)NN*4) + alup((size_t)EE*4) + alup((size_t)NN*FCOLS*2);
  size_t needA = alup((size_t)NN*QKV_COLS*4) + alup((size_t)NN*PTS_COLS*4) + common;
  size_t needB = alup((size_t)NN*QKV_COLS*2) + alup((size_t)NN*PTS_COLS*4) + common;
  size_t needC = alup((size_t)NN*QKV_COLS*2) + alup((size_t)NN*PTS_COLS*2) + common;

  if (ws_size >= needA)      run_all<float, float>(a, (char*)d_ws, stream);
  else if (ws_size >= needB) run_all<__hip_bfloat16, float>(a, (char*)d_ws, stream);
  else if (ws_size >= needC) run_all<__hip_bfloat16, __hip_bfloat16>(a, (char*)d_ws, stream);
  else diag_ws<<<1, 64, 0, stream>>>((float*)d_out, (float)((double)ws_size / (1024.0*1024.0)));
}